// Round 1
// 642.236 us; speedup vs baseline: 1.1313x; 1.1313x over previous
//
#include <hip/hip_runtime.h>

#define T_ROWS   1000000
#define D        82
#define NG       256
#define RPC      64            // rows per chunk
#define CHB      20992         // bytes per matrix per chunk (64*82*4)
#define NCHUNKS  15625         // 1e6 / 64
#define NBLOCKS  256

// ws layout: 6 double tables [256]
#define WSD_CNT 0
#define WSD_SP  256
#define WSD_SPP 512
#define WSD_SY  768
#define WSD_SYY 1024
#define WSD_SPY 1280

typedef const __attribute__((address_space(1))) unsigned int* gp1_t;
typedef __attribute__((address_space(3))) unsigned int* lp3_t;

// global -> LDS direct DMA, 16B per lane. LDS dest is wave-uniform base + lane*16.
__device__ __forceinline__ void gl16(const void* g, const void* l) {
    __builtin_amdgcn_global_load_lds((gp1_t)(unsigned long long)g,
                                     (lp3_t)(unsigned int)(unsigned long long)l,
                                     16, 0, 0);
}

// Fused kernel: pred = sqrt(sum_d w_d (x1-x2)^2) + one-pass per-group stats.
// 256 blocks (1/CU, LDS-pinned), each streams 64-row chunks through a 3-deep
// LDS ring with global_load_lds; counted vmcnt keeps prefetches in flight
// across raw s_barriers (never drain to 0 in the main loop).
__global__ __launch_bounds__(256) void fused_kernel(
    const float* __restrict__ X1, const float* __restrict__ X2,
    const float* __restrict__ Y,  const float* __restrict__ W,
    const int* __restrict__ mask, float* __restrict__ pred_out,
    double* __restrict__ wsd)
{
    // 3 ring buffers, each [X1 chunk 5248 floats][X2 chunk 5248 floats]
    __shared__ __align__(16) float sbuf[3][10496];
    __shared__ float t_cnt[NG], t_sp[NG], t_spp[NG], t_sy[NG], t_syy[NG], t_spy[NG];

    const int tid  = threadIdx.x;
    const int wid  = tid >> 6;
    const int lane = tid & 63;
    const int b    = blockIdx.x;

    t_cnt[tid] = 0.f; t_sp[tid]  = 0.f; t_spp[tid] = 0.f;
    t_sy[tid]  = 0.f; t_syy[tid] = 0.f; t_spy[tid] = 0.f;

    // thread -> (row, quarter): 4 lanes per row, quarter q covers elems [20q,20q+20) (+2 for q==3)
    const int rloc = tid >> 2;          // 0..63
    const int q    = tid & 3;
    const int e0   = q * 20;
    float wreg[20];
    #pragma unroll
    for (int k = 0; k < 20; ++k) wreg[k] = W[e0 + k];
    float w20 = 0.f, w21 = 0.f;
    if (q == 3) { w20 = W[80]; w21 = W[81]; }

    __syncthreads();   // tables initialized before any atomics (nothing in flight yet)

    const int nJ = (NCHUNKS - b + 255) >> 8;   // 61 or 62 chunks for this block

    // stage one 64-row chunk of X1+X2 into ring buffer bi.
    // Per matrix: 20 full 1KB wave-transfers + one 512B half (lanes<32).
    // Per-wave instr count: wave0 = 12, waves1-3 = 10.
    auto stage = [&](int c, int bi) {
        const char* g1 = (const char*)X1 + (size_t)c * CHB;
        const char* g2 = (const char*)X2 + (size_t)c * CHB;
        char* l = (char*)&sbuf[bi][0];
        for (int s = wid; s < 21; s += 4) {
            if (s < 20) {
                gl16(g1 + s * 1024 + lane * 16, l + s * 1024);
                gl16(g2 + s * 1024 + lane * 16, l + CHB + s * 1024);
            } else if (lane < 32) {
                gl16(g1 + 20480 + lane * 16, l + 20480);
                gl16(g2 + 20480 + lane * 16, l + CHB + 20480);
            }
        }
    };

    // prefetch mask/Y for chunk 0 (q==0 lanes own rows)
    int   mnext = 0; float ynext = 0.f;
    if (q == 0) { const int r0 = b * RPC + rloc; mnext = mask[r0]; ynext = Y[r0]; }

    // prologue: chunks 0 and 1 in flight
    stage(b, 0);
    stage(b + 256, 1);

    for (int j = 0; j < nJ; ++j) {
        const int c  = b + (j << 8);
        const int bi = j % 3;

        // Wait for chunk j's DMA. vmcnt(10) is safe: chunk j+1 alone contributes
        // >=10 strictly-younger VMEM ops per wave, and vmcnt retires in order,
        // so <=10 outstanding implies chunk j fully landed. Never 0 mid-loop.
        if (j == nJ - 1) asm volatile("s_waitcnt vmcnt(0)" ::: "memory");
        else             asm volatile("s_waitcnt vmcnt(10)" ::: "memory");
        __builtin_amdgcn_s_barrier();           // raw barrier: no vmcnt drain
        asm volatile("" ::: "memory");          // fence: no LDS reads hoist above barrier

        // issue chunk j+2 into buffer (j+2)%3 == (j-1)%3 (finished last iter by all waves)
        if (j + 2 < nJ) stage(b + ((j + 2) << 8), (j + 2) % 3);

        const int   mcur = mnext; const float ycur = ynext;
        if (q == 0 && j + 1 < nJ) {             // prefetch mask/Y for next chunk
            const int rn = (c + 256) * RPC + rloc;
            mnext = mask[rn]; ynext = Y[rn];
        }

        // compute: weighted squared-diff partial dot from LDS
        const float* row1 = &sbuf[bi][rloc * 82];
        const float* row2 = row1 + 5248;
        float acc = 0.f;
        #pragma unroll
        for (int k = 0; k < 20; k += 2) {
            const float2 a  = *(const float2*)(row1 + e0 + k);
            const float2 bb = *(const float2*)(row2 + e0 + k);
            const float d0 = a.x - bb.x, d1 = a.y - bb.y;
            acc += d0 * d0 * wreg[k];
            acc += d1 * d1 * wreg[k + 1];
        }
        if (q == 3) {                            // elems 80,81
            const float2 a  = *(const float2*)(row1 + 80);
            const float2 bb = *(const float2*)(row2 + 80);
            const float d0 = a.x - bb.x, d1 = a.y - bb.y;
            acc += d0 * d0 * w20 + d1 * d1 * w21;
        }
        acc += __shfl_xor(acc, 1);               // reduce across the 4 lanes of the row
        acc += __shfl_xor(acc, 2);

        if (q == 0) {
            const float p = sqrtf(acc);
            pred_out[c * RPC + rloc] = p;
            const int g = mcur;
            atomicAdd(&t_cnt[g], 1.f);
            atomicAdd(&t_sp [g], p);
            atomicAdd(&t_spp[g], p * p);
            atomicAdd(&t_sy [g], ycur);
            atomicAdd(&t_syy[g], ycur * ycur);
            atomicAdd(&t_spy[g], p * ycur);
        }
    }

    __syncthreads();   // drain everything; tables final
    atomicAdd(&wsd[WSD_CNT + tid], (double)t_cnt[tid]);
    atomicAdd(&wsd[WSD_SP  + tid], (double)t_sp [tid]);
    atomicAdd(&wsd[WSD_SPP + tid], (double)t_spp[tid]);
    atomicAdd(&wsd[WSD_SY  + tid], (double)t_sy [tid]);
    atomicAdd(&wsd[WSD_SYY + tid], (double)t_syy[tid]);
    atomicAdd(&wsd[WSD_SPY + tid], (double)t_spy[tid]);
}

// Per-group Pearson r from raw sums (double: kills the Sp^2 cancellation),
// then mean |r|.
__global__ void final_kernel(const double* __restrict__ wsd, float* __restrict__ out)
{
    __shared__ float red[NG];
    const int g = threadIdx.x;
    const double n   = wsd[WSD_CNT + g];
    const double sp  = wsd[WSD_SP  + g];
    const double spp = wsd[WSD_SPP + g];
    const double sy  = wsd[WSD_SY  + g];
    const double syy = wsd[WSD_SYY + g];
    const double spy = wsd[WSD_SPY + g];
    const double sxy = spy - sp * sy / n;
    const double sxx = spp - sp * sp / n;
    const double syc = syy - sy * sy / n;
    red[g] = (float)fabs(sxy / sqrt(sxx * syc));
    __syncthreads();
    for (int s = 128; s > 0; s >>= 1) {
        if (g < s) red[g] += red[g + s];
        __syncthreads();
    }
    if (g == 0) out[0] = red[0] / (float)NG;
}

extern "C" void kernel_launch(void* const* d_in, const int* in_sizes, int n_in,
                              void* d_out, int out_size, void* d_ws, size_t ws_size,
                              hipStream_t stream)
{
    const float* X1   = (const float*)d_in[0];
    const float* X2   = (const float*)d_in[1];
    const float* Y    = (const float*)d_in[2];
    const float* W    = (const float*)d_in[3];
    const int*   mask = (const int*)d_in[4];
    float* out = (float*)d_out;

    hipMemsetAsync(d_ws, 0, 6 * NG * sizeof(double), stream);
    fused_kernel<<<NBLOCKS, 256, 0, stream>>>(X1, X2, Y, W, mask, out + 1, (double*)d_ws);
    final_kernel<<<1, NG, 0, stream>>>((const double*)d_ws, out);
}

// Round 2
// 635.768 us; speedup vs baseline: 1.1429x; 1.0102x over previous
//
#include <hip/hip_runtime.h>

#define T_ROWS   1000000
#define D        82
#define NG       256
#define RPC      32             // rows per chunk
#define CHB      10496          // bytes per matrix per chunk (32*82*4)
#define CHF      2624           // floats per matrix per chunk
#define NCHUNKS  31250          // 1e6 / 32
#define NBLOCKS  512            // 2 blocks/CU (LDS ~69 KB)
#define NSET     8              // split of global atomic tables

// ws: NSET sets of 6 double tables [NG]
#define SET_STRIDE (6 * NG)
#define WSD_CNT 0
#define WSD_SP  (1 * NG)
#define WSD_SPP (2 * NG)
#define WSD_SY  (3 * NG)
#define WSD_SYY (4 * NG)
#define WSD_SPY (5 * NG)

typedef const __attribute__((address_space(1))) unsigned int* gp1_t;
typedef __attribute__((address_space(3))) unsigned int* lp3_t;

// global -> LDS direct DMA, 16B per active lane. LDS dest = wave-uniform base + lane*16.
__device__ __forceinline__ void gl16(const void* g, const void* l) {
    __builtin_amdgcn_global_load_lds((gp1_t)(unsigned long long)g,
                                     (lp3_t)(unsigned int)(unsigned long long)l,
                                     16, 0, 0);
}

// Fused: pred = sqrt(sum_d w_d (x1-x2)^2) + one-pass per-group raw sums.
// 512 blocks (2/CU), each streams 32-row chunks through a 3-deep LDS ring via
// global_load_lds; counted per-wave vmcnt keeps 2 chunks in flight across raw
// s_barriers. Two independent blocks per CU overlap each other's DMA stalls.
__global__ __launch_bounds__(256) void fused_kernel(
    const float* __restrict__ X1, const float* __restrict__ X2,
    const float* __restrict__ Y,  const float* __restrict__ W,
    const int* __restrict__ mask, float* __restrict__ pred_out,
    double* __restrict__ wsd)
{
    // 3 ring slots, each [X1 chunk 2624 floats][X2 chunk 2624 floats]
    __shared__ __align__(16) float sbuf[3][2 * CHF];
    __shared__ float t_cnt[NG], t_sp[NG], t_spp[NG], t_sy[NG], t_syy[NG], t_spy[NG];

    const int tid  = threadIdx.x;
    const int wid  = tid >> 6;
    const int lane = tid & 63;
    const int b    = blockIdx.x;

    t_cnt[tid] = 0.f; t_sp[tid]  = 0.f; t_spp[tid] = 0.f;
    t_sy[tid]  = 0.f; t_syy[tid] = 0.f; t_spy[tid] = 0.f;

    // thread -> (row, eighth): 8 lanes per row; q covers elems [10q,10q+10) (+2 for q==7)
    const int rloc = tid >> 3;          // 0..31
    const int q    = tid & 7;
    const int e0   = q * 10;
    float wreg[10];
    #pragma unroll
    for (int k = 0; k < 10; ++k) wreg[k] = W[e0 + k];
    float w80 = 0.f, w81 = 0.f;
    if (q == 7) { w80 = W[80]; w81 = W[81]; }

    __syncthreads();   // tables zeroed before any atomics

    const int nJ = (NCHUNKS - b + NBLOCKS - 1) / NBLOCKS;   // 61 or 62

    // stage one 32-row chunk of X1+X2 into ring slot bi.
    // Per matrix: 10 full 1KB wave-transfers + one 256B tail (lanes<16).
    // Per-wave instr count: w0=6, w1=6, w2=6, w3=4.
    auto stage = [&](int c, int bi) {
        const char* g1 = (const char*)X1 + (size_t)c * CHB;
        const char* g2 = (const char*)X2 + (size_t)c * CHB;
        char* l = (char*)&sbuf[bi][0];
        #pragma unroll
        for (int s0 = 0; s0 < 3; ++s0) {
            const int s = wid + 4 * s0;
            if (s < 10) {
                gl16(g1 + s * 1024 + lane * 16, l + s * 1024);
                gl16(g2 + s * 1024 + lane * 16, l + CHB + s * 1024);
            } else if (s == 10 && lane < 16) {
                gl16(g1 + 10240 + lane * 16, l + 10240);
                gl16(g2 + 10240 + lane * 16, l + CHB + 10240);
            }
        }
    };

    // prologue: chunk 0 staged, mask/Y for chunk 0, chunk 1 staged
    stage(b, 0);
    int mnext = 0; float ynext = 0.f;
    if (q == 0) { const int r0 = b * RPC + rloc; mnext = mask[r0]; ynext = Y[r0]; }
    stage(b + NBLOCKS, 1);

    for (int j = 0; j < nJ; ++j) {
        const int c  = b + j * NBLOCKS;
        const int bi = j % 3;

        // Wait until chunk j's DMA retired. Younger ops at this point are chunk
        // j+1's stage (6 or 4 per wave) [+ up to 2 mask/Y loads, counted
        // conservatively as already retired — over-wait by <=2, never a race].
        if (j == nJ - 1)   asm volatile("s_waitcnt vmcnt(0)" ::: "memory");
        else if (wid == 3) asm volatile("s_waitcnt vmcnt(4)" ::: "memory");
        else               asm volatile("s_waitcnt vmcnt(6)" ::: "memory");
        __builtin_amdgcn_s_barrier();           // raw barrier: no vmcnt drain
        asm volatile("" ::: "memory");          // no LDS reads hoist above barrier

        // stage chunk j+2 into slot (j+2)%3 == (j-1)%3 (all waves done with it)
        if (j + 2 < nJ) stage(b + (j + 2) * NBLOCKS, (j + 2) % 3);

        const int   mcur = mnext; const float ycur = ynext;
        if (q == 0 && j + 1 < nJ) {
            const int rn = (c + NBLOCKS) * RPC + rloc;
            mnext = mask[rn]; ynext = Y[rn];
        }

        // weighted squared-diff partial dot from LDS
        const float* row1 = &sbuf[bi][rloc * 82];
        const float* row2 = row1 + CHF;
        float acc = 0.f;
        #pragma unroll
        for (int k = 0; k < 10; k += 2) {
            const float2 a  = *(const float2*)(row1 + e0 + k);
            const float2 bb = *(const float2*)(row2 + e0 + k);
            const float d0 = a.x - bb.x, d1 = a.y - bb.y;
            acc += d0 * d0 * wreg[k];
            acc += d1 * d1 * wreg[k + 1];
        }
        if (q == 7) {                            // elems 80,81
            const float2 a  = *(const float2*)(row1 + 80);
            const float2 bb = *(const float2*)(row2 + 80);
            const float d0 = a.x - bb.x, d1 = a.y - bb.y;
            acc += d0 * d0 * w80 + d1 * d1 * w81;
        }
        acc += __shfl_xor(acc, 1);               // reduce across the 8 lanes of the row
        acc += __shfl_xor(acc, 2);
        acc += __shfl_xor(acc, 4);

        if (q == 0) {
            const float p = sqrtf(acc);
            pred_out[c * RPC + rloc] = p;
            const int g = mcur;
            atomicAdd(&t_cnt[g], 1.f);
            atomicAdd(&t_sp [g], p);
            atomicAdd(&t_spp[g], p * p);
            atomicAdd(&t_sy [g], ycur);
            atomicAdd(&t_syy[g], ycur * ycur);
            atomicAdd(&t_spy[g], p * ycur);
        }
    }

    __syncthreads();   // tables final
    double* dst = wsd + (size_t)(b & (NSET - 1)) * SET_STRIDE;
    atomicAdd(&dst[WSD_CNT + tid], (double)t_cnt[tid]);
    atomicAdd(&dst[WSD_SP  + tid], (double)t_sp [tid]);
    atomicAdd(&dst[WSD_SPP + tid], (double)t_spp[tid]);
    atomicAdd(&dst[WSD_SY  + tid], (double)t_sy [tid]);
    atomicAdd(&dst[WSD_SYY + tid], (double)t_syy[tid]);
    atomicAdd(&dst[WSD_SPY + tid], (double)t_spy[tid]);
}

// Per-group Pearson r from raw sums (double kills the Sp^2 cancellation), mean |r|.
__global__ void final_kernel(const double* __restrict__ wsd, float* __restrict__ out)
{
    __shared__ float red[NG];
    const int g = threadIdx.x;
    double n = 0, sp = 0, spp = 0, sy = 0, syy = 0, spy = 0;
    #pragma unroll
    for (int s = 0; s < NSET; ++s) {
        const double* t = wsd + (size_t)s * SET_STRIDE;
        n   += t[WSD_CNT + g];
        sp  += t[WSD_SP  + g];
        spp += t[WSD_SPP + g];
        sy  += t[WSD_SY  + g];
        syy += t[WSD_SYY + g];
        spy += t[WSD_SPY + g];
    }
    const double sxy = spy - sp * sy / n;
    const double sxx = spp - sp * sp / n;
    const double syc = syy - sy * sy / n;
    red[g] = (float)fabs(sxy / sqrt(sxx * syc));
    __syncthreads();
    for (int s = 128; s > 0; s >>= 1) {
        if (g < s) red[g] += red[g + s];
        __syncthreads();
    }
    if (g == 0) out[0] = red[0] / (float)NG;
}

extern "C" void kernel_launch(void* const* d_in, const int* in_sizes, int n_in,
                              void* d_out, int out_size, void* d_ws, size_t ws_size,
                              hipStream_t stream)
{
    const float* X1   = (const float*)d_in[0];
    const float* X2   = (const float*)d_in[1];
    const float* Y    = (const float*)d_in[2];
    const float* W    = (const float*)d_in[3];
    const int*   mask = (const int*)d_in[4];
    float* out = (float*)d_out;

    hipMemsetAsync(d_ws, 0, NSET * SET_STRIDE * sizeof(double), stream);
    fused_kernel<<<NBLOCKS, 256, 0, stream>>>(X1, X2, Y, W, mask, out + 1, (double*)d_ws);
    final_kernel<<<1, NG, 0, stream>>>((const double*)d_ws, out);
}